// Round 7
// baseline (187.558 us; speedup 1.0000x reference)
//
#include <hip/hip_runtime.h>

#define DDIM 1024
#define NEXP 64
#define TOPK 8
#define BK 32
#define ROWS 32
#define NTILE 32
#define XBUFSZ 16384
#define WBASE 32768
#define WTILE 12288
#define TAUF 5.0e-3f
#define TAUB 1.0e-2f

typedef __attribute__((ext_vector_type(8))) short short8;
typedef __attribute__((ext_vector_type(4))) float f32x4;

static __device__ __forceinline__ unsigned int f2u(float f) { return __builtin_bit_cast(unsigned int, f); }
static __device__ __forceinline__ float u2f(unsigned int u) { return __builtin_bit_cast(float, u); }

static __device__ __forceinline__ unsigned short bf_hi_rne(float x) {
    unsigned int u = f2u(x);
    return (unsigned short)((u + (0x7FFFu + ((u >> 16) & 1u))) >> 16);
}

static __device__ __forceinline__ void split2(float x, unsigned short& h, unsigned short& l) {
    unsigned int u = f2u(x);
    unsigned int uh = (u + (0x7FFFu + ((u >> 16) & 1u))) & 0xFFFF0000u;
    h = (unsigned short)(uh >> 16);
    float rem = x - u2f(uh);
    l = (unsigned short)(f2u(rem) >> 16);
}

// Prologue (unchanged from R6): pre-permute W into the swizzled LDS image, DMA'd linearly.
// tile t, array a (0=wn_hi,1=wn_lo,2=we_hi), expert e, 16B chunk c:
//   ws byte = t*12288 + a*4096 + ((e*64 + c*16) ^ ((e&7)<<4))
__global__ __launch_bounds__(256) void conv_w_kernel(
    const float* __restrict__ Wn, const float* __restrict__ We, char* __restrict__ wsW)
{
    int g = blockIdx.x * 256 + threadIdx.x;   // 0..8191
    int e = g >> 7, c128 = g & 127;
    int k = c128 << 3;
    int t = k >> 5, c = (k >> 3) & 3;
    const float* np = Wn + (size_t)e * DDIM + k;
    const float* ep = We + (size_t)e * DDIM + k;
    f32x4 n0 = ((const f32x4*)np)[0], n1 = ((const f32x4*)np)[1];
    f32x4 e0 = ((const f32x4*)ep)[0], e1 = ((const f32x4*)ep)[1];
    short8 nh, nl, eh;
#pragma unroll
    for (int i = 0; i < 4; i++) { unsigned short h, l; split2(n0[i], h, l); nh[i] = (short)h; nl[i] = (short)l; }
#pragma unroll
    for (int i = 0; i < 4; i++) { unsigned short h, l; split2(n1[i], h, l); nh[i + 4] = (short)h; nl[i + 4] = (short)l; }
#pragma unroll
    for (int i = 0; i < 4; i++) eh[i] = (short)bf_hi_rne(e0[i]);
#pragma unroll
    for (int i = 0; i < 4; i++) eh[i + 4] = (short)bf_hi_rne(e1[i]);
    size_t dst = (size_t)t * WTILE + (size_t)((e * 64 + c * 16) ^ ((e & 7) << 4));
    *(short8*)(wsW + dst)        = nh;
    *(short8*)(wsW + dst + 4096) = nl;
    *(short8*)(wsW + dst + 8192) = eh;
}

// LDS (69632 B -> 2 blocks/CU):
//   x slab dbuf [2][32 rows][128 f32] @0, 16KB each, XOR-swizzled (16B units, ^((row&7)<<4))
//   W  tri-buf @32768, 3 x 12288 (wn_hi|wn_lo|we_hi 4KB each), swizzled (R6 layout)
//   epilogue overlay @0: s_log[32][65], s_exp, s_gap, s_vb
// x DMA: per slab 16 x 1KB instructions -> 512B contiguous burst per row (DRAM page locality).
template <int PRE>
__global__ __launch_bounds__(256, 2) void moe_kernel(
    const float* __restrict__ x, const float* __restrict__ Wn,
    const float* __restrict__ bn, const float* __restrict__ We,
    const char* __restrict__ wsW, float* __restrict__ out)
{
    __shared__ __align__(16) char smem[69632];

    const int tid = threadIdx.x;
    const int wid = tid >> 6;
    const int lane = tid & 63;
    const int fr = lane & 15;
    const int fq = lane >> 4;
    const int blockRow = blockIdx.x * ROWS;

    const int rh16 = (wid >> 1) * 16;       // wave's row base (0 or 16)
    const int e2 = (wid & 1) * 2;           // wave's expert col-tile pair base (ct 0-1 or 2-3)

    // ---- x DMA source pointers (pre-swizzled, T21): instruction i covers LDS window
    // (wid*4+i)*1024; lane writes LDS byte base+lane*16; that byte holds
    // row = (wid*4+i)*2 + (lane>>5), within-row byte w = ((lane&31)*16) ^ ((row&7)<<4).
    const int l5 = lane >> 5, lw = lane & 31;
    const int r0 = (wid * 4 + 0) * 2 + l5;
    const int r1 = (wid * 4 + 1) * 2 + l5;
    const int r2 = (wid * 4 + 2) * 2 + l5;
    const int r3 = (wid * 4 + 3) * 2 + l5;
    const char* xg0 = (const char*)x + (size_t)(blockRow + r0) * 4096 + ((lw * 16) ^ ((r0 & 7) << 4));
    const char* xg1 = (const char*)x + (size_t)(blockRow + r1) * 4096 + ((lw * 16) ^ ((r1 & 7) << 4));
    const char* xg2 = (const char*)x + (size_t)(blockRow + r2) * 4096 + ((lw * 16) ^ ((r2 & 7) << 4));
    const char* xg3 = (const char*)x + (size_t)(blockRow + r3) * 4096 + ((lw * 16) ^ ((r3 & 7) << 4));
    const int widx4k = wid * 4096;

    // ---- x fragment read offsets: addr = row*512 + p*128 + ((fq*32 [+16]) ^ ((row&7)<<4))
    const int xrow = rh16 + fr;
    const int xrb = xrow * 512;
    const int xsw = (xrow & 7) << 4;
    const int xfo0 = (fq * 32) ^ xsw;
    const int xfo1 = (fq * 32 + 16) ^ xsw;

    // ---- W ds_read offset (R6 layout): e = ct_g*16+fr -> ct_g*1024 + (fr*64+fq*16)^((fr&7)<<4)
    const int xo = (fr * 64 + fq * 16) ^ ((fr & 7) << 4);
    const int wo0 = e2 * 1024 + xo;

    f32x4 accN[2], accE[2];
#pragma unroll
    for (int c = 0; c < 2; c++) { accN[c] = f32x4{0.f,0.f,0.f,0.f}; accE[c] = f32x4{0.f,0.f,0.f,0.f}; }

#define XDMA(S, XB) { \
    char* ld_ = smem + (XB) * XBUFSZ + widx4k; \
    __builtin_amdgcn_global_load_lds((const __attribute__((address_space(1))) void*)(xg0 + (S) * 512), (__attribute__((address_space(3))) void*)(ld_），16, 0, 0); \
    }

#undef XDMA
#define XDMA(S, XB) { \
    char* ld_ = smem + (XB) * XBUFSZ + widx4k; \
    __builtin_amdgcn_global_load_lds((const __attribute__((address_space(1))) void*)(xg0 + (S) * 512), (__attribute__((address_space(3))) void*)(ld_       ), 16, 0, 0); \
    __builtin_amdgcn_global_load_lds((const __attribute__((address_space(1))) void*)(xg1 + (S) * 512), (__attribute__((address_space(3))) void*)(ld_ + 1024), 16, 0, 0); \
    __builtin_amdgcn_global_load_lds((const __attribute__((address_space(1))) void*)(xg2 + (S) * 512), (__attribute__((address_space(3))) void*)(ld_ + 2048), 16, 0, 0); \
    __builtin_amdgcn_global_load_lds((const __attribute__((address_space(1))) void*)(xg3 + (S) * 512), (__attribute__((address_space(3))) void*)(ld_ + 3072), 16, 0, 0); }

#define WDMA(T, WB) { \
    const char* gs_ = wsW + (size_t)(T) * WTILE + wid * 1024 + lane * 16; \
    char* ls_ = smem + WBASE + (WB) * WTILE + wid * 1024; \
    _Pragma("unroll") \
    for (int a_ = 0; a_ < 3; a_++) \
        __builtin_amdgcn_global_load_lds( \
            (const __attribute__((address_space(1))) void*)(gs_ + a_ * 4096), \
            (__attribute__((address_space(3))) void*)(ls_ + a_ * 4096), 16, 0, 0); }

#define TCOMP(T) { \
    const char* xbp_ = smem + (((T) >> 2) & 1) * XBUFSZ + xrb + ((T) & 3) * 128; \
    f32x4 v0_ = *(const f32x4*)(xbp_ + xfo0); \
    f32x4 v1_ = *(const f32x4*)(xbp_ + xfo1); \
    short8 xh_; \
    _Pragma("unroll") for (int i = 0; i < 4; i++) xh_[i]     = (short)bf_hi_rne(v0_[i]); \
    _Pragma("unroll") for (int i = 0; i < 4; i++) xh_[i + 4] = (short)bf_hi_rne(v1_[i]); \
    const char* wb_ = smem + WBASE + ((T) % 3) * WTILE; \
    _Pragma("unroll") \
    for (int c_ = 0; c_ < 2; c_++) { \
        short8 wh_ = *(const short8*)(wb_ +        wo0 + c_ * 1024); \
        short8 wl_ = *(const short8*)(wb_ + 4096 + wo0 + c_ * 1024); \
        short8 we_ = *(const short8*)(wb_ + 8192 + wo0 + c_ * 1024); \
        accN[c_] = __builtin_amdgcn_mfma_f32_16x16x32_bf16(xh_, wh_, accN[c_], 0, 0, 0); \
        accN[c_] = __builtin_amdgcn_mfma_f32_16x16x32_bf16(xh_, wl_, accN[c_], 0, 0, 0); \
        accE[c_] = __builtin_amdgcn_mfma_f32_16x16x32_bf16(xh_, we_, accE[c_], 0, 0, 0); \
    } }

// tile T: [maybe XDMA slab (T>>2)+1] ; compute ; lgkm(0) ; counted vmcnt ; barrier ; [maybe WDMA T+3]
#define TILE(T, DOX, DOW, VMSTR) { \
    if (DOX) { XDMA(((T) >> 2) + 1, (((T) >> 2) + 1) & 1) } \
    TCOMP(T) \
    asm volatile("s_waitcnt lgkmcnt(0)" ::: "memory"); \
    asm volatile("s_waitcnt " VMSTR ::: "memory"); \
    __builtin_amdgcn_s_barrier(); \
    asm volatile("" ::: "memory"); \
    if (DOW) { WDMA((T) + 3, ((T) + 3) % 3) } }

    if constexpr (PRE) {
        // prologue: x slabs 0,1 (8 ops) + W tiles 0,1,2 (9 ops); wait so x0+W0 done (W1,W2 = 6 newer)
        XDMA(0, 0)
        XDMA(1, 1)
        WDMA(0, 0) WDMA(1, 1) WDMA(2, 2)
        asm volatile("s_waitcnt vmcnt(6)" ::: "memory");
        __builtin_amdgcn_s_barrier();
        asm volatile("" ::: "memory");

        // vmcnt(N): N = 3 + 4*[XDMA@T] + 4*[XDMA@T-1]; XDMA at T in {4,8,12,16,20,24}; tail drains.
        TILE(0, 0, 1, "vmcnt(3)")  TILE(1, 0, 1, "vmcnt(3)")  TILE(2, 0, 1, "vmcnt(3)")  TILE(3, 0, 1, "vmcnt(3)")
        TILE(4, 1, 1, "vmcnt(7)")  TILE(5, 0, 1, "vmcnt(7)")  TILE(6, 0, 1, "vmcnt(3)")  TILE(7, 0, 1, "vmcnt(3)")
        TILE(8, 1, 1, "vmcnt(7)")  TILE(9, 0, 1, "vmcnt(7)")  TILE(10, 0, 1, "vmcnt(3)") TILE(11, 0, 1, "vmcnt(3)")
        TILE(12, 1, 1, "vmcnt(7)") TILE(13, 0, 1, "vmcnt(7)") TILE(14, 0, 1, "vmcnt(3)") TILE(15, 0, 1, "vmcnt(3)")
        TILE(16, 1, 1, "vmcnt(7)") TILE(17, 0, 1, "vmcnt(7)") TILE(18, 0, 1, "vmcnt(3)") TILE(19, 0, 1, "vmcnt(3)")
        TILE(20, 1, 1, "vmcnt(7)") TILE(21, 0, 1, "vmcnt(7)") TILE(22, 0, 1, "vmcnt(3)") TILE(23, 0, 1, "vmcnt(3)")
        TILE(24, 1, 1, "vmcnt(7)") TILE(25, 0, 1, "vmcnt(7)") TILE(26, 0, 1, "vmcnt(3)") TILE(27, 0, 1, "vmcnt(3)")
        TILE(28, 0, 1, "vmcnt(3)") TILE(29, 0, 0, "vmcnt(3)") TILE(30, 0, 0, "vmcnt(0)")
        TCOMP(31)
    } else {
        // fallback: no LDS in main loop; per-lane direct loads + in-kernel conversion (slow, correct)
        for (int t = 0; t < NTILE; ++t) {
            const float* xp = x + (size_t)(blockRow + rh16 + fr) * DDIM + t * BK + fq * 8;
            f32x4 v0 = ((const f32x4*)xp)[0], v1 = ((const f32x4*)xp)[1];
            short8 xh;
#pragma unroll
            for (int i = 0; i < 4; i++) xh[i]     = (short)bf_hi_rne(v0[i]);
#pragma unroll
            for (int i = 0; i < 4; i++) xh[i + 4] = (short)bf_hi_rne(v1[i]);
#pragma unroll
            for (int c = 0; c < 2; c++) {
                const int e = (e2 + c) * 16 + fr;
                const float* np = Wn + (size_t)e * DDIM + t * BK + fq * 8;
                const float* ep = We + (size_t)e * DDIM + t * BK + fq * 8;
                f32x4 n0 = ((const f32x4*)np)[0], n1 = ((const f32x4*)np)[1];
                f32x4 e0 = ((const f32x4*)ep)[0], e1 = ((const f32x4*)ep)[1];
                short8 wh, wl, we;
#pragma unroll
                for (int i = 0; i < 4; i++) { unsigned short h, l; split2(n0[i], h, l); wh[i] = (short)h; wl[i] = (short)l; }
#pragma unroll
                for (int i = 0; i < 4; i++) { unsigned short h, l; split2(n1[i], h, l); wh[i + 4] = (short)h; wl[i + 4] = (short)l; }
#pragma unroll
                for (int i = 0; i < 4; i++) we[i] = (short)bf_hi_rne(e0[i]);
#pragma unroll
                for (int i = 0; i < 4; i++) we[i + 4] = (short)bf_hi_rne(e1[i]);
                accN[c] = __builtin_amdgcn_mfma_f32_16x16x32_bf16(xh, wh, accN[c], 0, 0, 0);
                accN[c] = __builtin_amdgcn_mfma_f32_16x16x32_bf16(xh, wl, accN[c], 0, 0, 0);
                accE[c] = __builtin_amdgcn_mfma_f32_16x16x32_bf16(xh, we, accE[c], 0, 0, 0);
            }
        }
    }
    __syncthreads();

    // ---- epilogue overlay (x region)
    float* s_log = (float*)smem;                 // [32][65]
    float* s_exp = (float*)(smem + 8320);        // [32][65]
    float* s_gap = (float*)(smem + 16640);       // [32]
    float* s_vb  = (float*)(smem + 16768);       // [32]

#pragma unroll
    for (int c = 0; c < 2; c++) {
        const int e = (e2 + c) * 16 + fr;
        const float be = bn[e];
#pragma unroll
        for (int j = 0; j < 4; j++) {
            const int r = rh16 + fq * 4 + j;     // C/D: col=lane&15, row=(lane>>4)*4+j
            s_log[r * 65 + e] = accN[c][j] + be;
            s_exp[r * 65 + e] = accE[c][j];
        }
    }
    __syncthreads();

    auto wave_max = [&](float c) {
#pragma unroll
        for (int off = 32; off >= 1; off >>= 1) c = fmaxf(c, __shfl_xor(c, off));
        return c;
    };
    auto wave_sum = [&](float c) {
#pragma unroll
        for (int off = 32; off >= 1; off >>= 1) c += __shfl_xor(c, off);
        return c;
    };

    // array-free wave-parallel top-8 + softmax + weighted sum; one row per pass.
    auto select_row = [&](int r, bool writeGap) {
        const float v = s_log[r * 65 + lane];
        const float g = s_exp[r * 65 + lane];
        unsigned long long act = ~0ull, sel = 0ull;
        float m0 = 0.f, v8 = 0.f;
#pragma unroll
        for (int tt = 0; tt < TOPK; tt++) {
            float c = ((act >> lane) & 1ull) ? v : -3.0e38f;
            c = wave_max(c);
            unsigned long long elig = __ballot(v == c) & act;   // lowest index wins ties
            int win = __builtin_ctzll(elig);
            sel |= 1ull << win;
            act &= ~(1ull << win);
            if (tt == 0) m0 = c;
            v8 = c;
        }
        float c9 = ((act >> lane) & 1ull) ? v : -3.0e38f;
        float v9 = wave_max(c9);
        float w = ((sel >> lane) & 1ull) ? __expf(v - m0) : 0.f;
        float Z = wave_sum(w);
        float O = wave_sum(w * g);
        if (lane == 0) {
            out[blockRow + r] = O / Z;
            if (writeGap) { s_gap[r] = v8 - v9; s_vb[r] = 0.5f * (v8 + v9); }
        }
    };

    for (int rr = 0; rr < 8; ++rr) select_row(wid * 8 + rr, true);
    __syncthreads();

    // fp64 fixup for near-tie rows, distributed: wave w handles rows r%4==w
    for (int r = wid; r < ROWS; r += 4) {
        if (!(s_gap[r] < TAUF)) continue;
        const float vbr = s_vb[r];
        const float ve = s_log[r * 65 + lane];
        unsigned long long cand = __ballot(fabsf(ve - vbr) <= TAUB);
        const f32x4* xq = (const f32x4*)(x + (size_t)(blockRow + r) * DDIM) + lane * 4;
        const f32x4 xv0 = xq[0], xv1 = xq[1], xv2 = xq[2], xv3 = xq[3];
        while (cand) {
            const int ce = __builtin_ctzll(cand);
            cand &= cand - 1;
            const f32x4* wq = (const f32x4*)(Wn + (size_t)ce * DDIM) + lane * 4;
            const f32x4 w0 = wq[0], w1 = wq[1], w2 = wq[2], w3 = wq[3];
            double s = 0.0;
#pragma unroll
            for (int i = 0; i < 4; i++) s = fma((double)xv0[i], (double)w0[i], s);
#pragma unroll
            for (int i = 0; i < 4; i++) s = fma((double)xv1[i], (double)w1[i], s);
#pragma unroll
            for (int i = 0; i < 4; i++) s = fma((double)xv2[i], (double)w2[i], s);
#pragma unroll
            for (int i = 0; i < 4; i++) s = fma((double)xv3[i], (double)w3[i], s);
#pragma unroll
            for (int off = 32; off > 0; off >>= 1) s += __shfl_xor(s, off);
            s += (double)bn[ce];
            if (lane == 0) s_log[r * 65 + ce] = (float)s;
        }
    }
    __syncthreads();

    // re-select flagged rows with corrected logits
    for (int rr = 0; rr < 8; ++rr) {
        const int r = wid * 8 + rr;
        if (s_gap[r] < TAUF) select_row(r, false);
    }
}

extern "C" void kernel_launch(void* const* d_in, const int* in_sizes, int n_in,
                              void* d_out, int out_size, void* d_ws, size_t ws_size,
                              hipStream_t stream)
{
    // setup_inputs order: x, Wg, bg, Wn, bn, We, noise  (Wg/bg/noise are dead code)
    const float* x  = (const float*)d_in[0];
    const float* Wn = (const float*)d_in[3];
    const float* bn = (const float*)d_in[4];
    const float* We = (const float*)d_in[5];
    float* out = (float*)d_out;

    const int B = in_sizes[0] / DDIM;           // 65536
    const int grid = B / ROWS;                  // 2048

    const size_t need = (size_t)NTILE * WTILE;  // 384 KiB permuted W
    if (d_ws != nullptr && ws_size >= need) {
        conv_w_kernel<<<(NEXP * DDIM / 8) / 256, 256, 0, stream>>>(Wn, We, (char*)d_ws);
        moe_kernel<1><<<grid, 256, 0, stream>>>(x, Wn, bn, We, (const char*)d_ws, out);
    } else {
        moe_kernel<0><<<grid, 256, 0, stream>>>(x, Wn, bn, We, nullptr, out);
    }
}

// Round 8
// 164.410 us; speedup vs baseline: 1.1408x; 1.1408x over previous
//
#include <hip/hip_runtime.h>

#define DDIM 1024
#define NEXP 64
#define TOPK 8
#define BK 32
#define ROWS 32
#define NTILE 32
#define WTILE 12288
#define TAUF 5.0e-3f
#define TAUB 1.0e-2f

typedef __attribute__((ext_vector_type(8))) short short8;
typedef __attribute__((ext_vector_type(4))) float f32x4;

static __device__ __forceinline__ unsigned int f2u(float f) { return __builtin_bit_cast(unsigned int, f); }
static __device__ __forceinline__ float u2f(unsigned int u) { return __builtin_bit_cast(float, u); }

static __device__ __forceinline__ unsigned short bf_hi_rne(float x) {
    unsigned int u = f2u(x);
    return (unsigned short)((u + (0x7FFFu + ((u >> 16) & 1u))) >> 16);
}

static __device__ __forceinline__ void split2(float x, unsigned short& h, unsigned short& l) {
    unsigned int u = f2u(x);
    unsigned int uh = (u + (0x7FFFu + ((u >> 16) & 1u))) & 0xFFFF0000u;
    h = (unsigned short)(uh >> 16);
    float rem = x - u2f(uh);
    l = (unsigned short)(f2u(rem) >> 16);
}

// Prologue (R4 layout): pre-permute W into per-(tile,wave) register-load order.
// tile t, wave q, array a (0=wn_hi,1=wn_lo,2=we_hi), lane l = c*16 + (e&15):
//   ws byte = t*12288 + q*3072 + a*1024 + l*16   (1KB contiguous per wave-array)
__global__ __launch_bounds__(256) void conv_w_kernel(
    const float* __restrict__ Wn, const float* __restrict__ We, char* __restrict__ wsW)
{
    int g = blockIdx.x * 256 + threadIdx.x;   // 0..8191
    int e = g >> 7, c128 = g & 127;
    int k = c128 << 3;
    int t = k >> 5, c = (k >> 3) & 3;
    const float* np = Wn + (size_t)e * DDIM + k;
    const float* ep = We + (size_t)e * DDIM + k;
    f32x4 n0 = ((const f32x4*)np)[0], n1 = ((const f32x4*)np)[1];
    f32x4 e0 = ((const f32x4*)ep)[0], e1 = ((const f32x4*)ep)[1];
    short8 nh, nl, eh;
#pragma unroll
    for (int i = 0; i < 4; i++) { unsigned short h, l; split2(n0[i], h, l); nh[i] = (short)h; nl[i] = (short)l; }
#pragma unroll
    for (int i = 0; i < 4; i++) { unsigned short h, l; split2(n1[i], h, l); nh[i + 4] = (short)h; nl[i + 4] = (short)l; }
#pragma unroll
    for (int i = 0; i < 4; i++) eh[i] = (short)bf_hi_rne(e0[i]);
#pragma unroll
    for (int i = 0; i < 4; i++) eh[i + 4] = (short)bf_hi_rne(e1[i]);
    size_t dst = (size_t)t * WTILE + (size_t)(e >> 4) * 3072 + (size_t)((c * 16 + (e & 15)) * 16);
    *(short8*)(wsW + dst)        = nh;
    *(short8*)(wsW + dst + 1024) = nl;
    *(short8*)(wsW + dst + 2048) = eh;
}

// LDS (65536 B -> 2 blocks/CU): x image [32 rows][1024] bf16-hi, row stride 2048 B,
// byte col XOR-swizzled by ((row&15)<<4).  Epilogue overlay (after syncthreads):
// s_log[32][65] @0, s_exp @8320, s_gap @16640, s_vb @16768.
// Phase 1: contiguous m13-style stream of the block's 128 KB slab (one pass, 4-deep prefetch).
// Phase 2: NO barriers; W -> registers from permuted ws (counted vmcnt, no other VM ops).
template <int PRE>
__global__ __launch_bounds__(256, 2) void moe_kernel(
    const float* __restrict__ x, const float* __restrict__ Wn,
    const float* __restrict__ bn, const float* __restrict__ We,
    const char* __restrict__ wsW, float* __restrict__ out)
{
    __shared__ __align__(16) char smem[65536];

    const int tid = threadIdx.x;
    const int wid = tid >> 6;
    const int lane = tid & 63;
    const int fr = lane & 15;
    const int fq = lane >> 4;
    const int blockRow = blockIdx.x * ROWS;

    // ---- phase 1: stream 32 rows contiguously. round r: 256 threads cover rows 2r,2r+1.
    const int trow = tid >> 7;                 // 0/1 within round
    const int tcolb = (tid & 127) * 16;        // byte col in bf16 image
    const float* xg = x + (size_t)(blockRow + trow) * DDIM + (tid & 127) * 8;

    f32x4 a0, a1, b0, b1, c0, c1, d0, d1;      // 4 named prefetch pairs (rule #20)

#define SLOAD(P, R) { const float* p_ = xg + (size_t)(R) * 2048; \
    P##0 = ((const f32x4*)p_)[0]; P##1 = ((const f32x4*)p_)[1]; }
#define SWRITE(P, R) { short8 h_; \
    _Pragma("unroll") for (int i = 0; i < 4; i++) h_[i]     = (short)bf_hi_rne(P##0[i]); \
    _Pragma("unroll") for (int i = 0; i < 4; i++) h_[i + 4] = (short)bf_hi_rne(P##1[i]); \
    const int wr_ = 2 * (R) + trow; \
    *(short8*)(smem + wr_ * 2048 + (tcolb ^ ((wr_ & 15) << 4))) = h_; }

    SLOAD(a, 0) SLOAD(b, 1) SLOAD(c, 2) SLOAD(d, 3)
    SWRITE(a, 0)  SLOAD(a, 4)  SWRITE(b, 1)  SLOAD(b, 5)
    SWRITE(c, 2)  SLOAD(c, 6)  SWRITE(d, 3)  SLOAD(d, 7)
    SWRITE(a, 4)  SLOAD(a, 8)  SWRITE(b, 5)  SLOAD(b, 9)
    SWRITE(c, 6)  SLOAD(c, 10) SWRITE(d, 7)  SLOAD(d, 11)
    SWRITE(a, 8)  SLOAD(a, 12) SWRITE(b, 9)  SLOAD(b, 13)
    SWRITE(c, 10) SLOAD(c, 14) SWRITE(d, 11) SLOAD(d, 15)
    SWRITE(a, 12) SWRITE(b, 13) SWRITE(c, 14) SWRITE(d, 15)
    __syncthreads();

    // ---- phase 2: barrier-free K-loop. wave owns experts wid*16..+15, all 32 rows.
    f32x4 accN[2], accE[2];
#pragma unroll
    for (int rt = 0; rt < 2; rt++) { accN[rt] = f32x4{0.f,0.f,0.f,0.f}; accE[rt] = f32x4{0.f,0.f,0.f,0.f}; }

    short8 whA, wlA, ehA, whB, wlB, ehB, whC, wlC, ehC;
    const char* wbase = wsW + wid * 3072 + lane * 16;
    const char* xr0 = smem + fr * 2048;          // row fr
    const char* xr1 = smem + (16 + fr) * 2048;   // row 16+fr; (16+fr)&15 == fr -> same XOR
    const int xs = (fr & 15) << 4;
    const int xco = fq * 16;

#define WLOAD(S, T) { \
    if constexpr (PRE) { \
        const char* wp_ = wbase + (size_t)(T) * WTILE; \
        wh##S = *(const short8*)(wp_); \
        wl##S = *(const short8*)(wp_ + 1024); \
        eh##S = *(const short8*)(wp_ + 2048); \
    } else { \
        const float* np_ = Wn + (size_t)(wid * 16 + fr) * DDIM + (T) * BK + fq * 8; \
        const float* ep_ = We + (size_t)(wid * 16 + fr) * DDIM + (T) * BK + fq * 8; \
        f32x4 n0_ = ((const f32x4*)np_)[0], n1_ = ((const f32x4*)np_)[1]; \
        f32x4 e0_ = ((const f32x4*)ep_)[0], e1_ = ((const f32x4*)ep_)[1]; \
        for (int i = 0; i < 4; i++) { unsigned short h_, l_; split2(n0_[i], h_, l_); wh##S[i] = (short)h_; wl##S[i] = (short)l_; } \
        for (int i = 0; i < 4; i++) { unsigned short h_, l_; split2(n1_[i], h_, l_); wh##S[i + 4] = (short)h_; wl##S[i + 4] = (short)l_; } \
        for (int i = 0; i < 4; i++) eh##S[i] = (short)bf_hi_rne(e0_[i]); \
        for (int i = 0; i < 4; i++) eh##S[i + 4] = (short)bf_hi_rne(e1_[i]); \
    } }

#define COMPUTE(T, S) { \
    const int xo_ = (((T) * 64 + xco) ^ xs); \
    short8 x0_ = *(const short8*)(xr0 + xo_); \
    short8 x1_ = *(const short8*)(xr1 + xo_); \
    accN[0] = __builtin_amdgcn_mfma_f32_16x16x32_bf16(x0_, wh##S, accN[0], 0, 0, 0); \
    accN[0] = __builtin_amdgcn_mfma_f32_16x16x32_bf16(x0_, wl##S, accN[0], 0, 0, 0); \
    accE[0] = __builtin_amdgcn_mfma_f32_16x16x32_bf16(x0_, eh##S, accE[0], 0, 0, 0); \
    accN[1] = __builtin_amdgcn_mfma_f32_16x16x32_bf16(x1_, wh##S, accN[1], 0, 0, 0); \
    accN[1] = __builtin_amdgcn_mfma_f32_16x16x32_bf16(x1_, wl##S, accN[1], 0, 0, 0); \
    accE[1] = __builtin_amdgcn_mfma_f32_16x16x32_bf16(x1_, eh##S, accE[1], 0, 0, 0); }

    WLOAD(A, 0) WLOAD(B, 1) WLOAD(C, 2)
#pragma unroll 1
    for (int p = 0; p < 10; ++p) {
        const int t0 = 3 * p;
        COMPUTE(t0, A)     if (t0 + 3 < NTILE) { WLOAD(A, t0 + 3) }
        COMPUTE(t0 + 1, B) if (t0 + 4 < NTILE) { WLOAD(B, t0 + 4) }
        COMPUTE(t0 + 2, C) if (t0 + 5 < NTILE) { WLOAD(C, t0 + 5) }
    }
    COMPUTE(30, A)
    COMPUTE(31, B)
    __syncthreads();                 // all waves done reading x image before overlay

    // ---- epilogue overlay
    float* s_log = (float*)smem;                 // [32][65]
    float* s_exp = (float*)(smem + 8320);        // [32][65]
    float* s_gap = (float*)(smem + 16640);       // [32]
    float* s_vb  = (float*)(smem + 16768);       // [32]

    const int ecol = wid * 16 + fr;
    const float be = bn[ecol];
#pragma unroll
    for (int rt = 0; rt < 2; rt++) {
#pragma unroll
        for (int j = 0; j < 4; j++) {
            const int r = rt * 16 + fq * 4 + j;  // C/D: col=lane&15, row=(lane>>4)*4+j
            s_log[r * 65 + ecol] = accN[rt][j] + be;
            s_exp[r * 65 + ecol] = accE[rt][j];
        }
    }
    __syncthreads();

    auto wave_max = [&](float c) {
#pragma unroll
        for (int off = 32; off >= 1; off >>= 1) c = fmaxf(c, __shfl_xor(c, off));
        return c;
    };
    auto wave_sum = [&](float c) {
#pragma unroll
        for (int off = 32; off >= 1; off >>= 1) c += __shfl_xor(c, off);
        return c;
    };

    // array-free wave-parallel top-8 + softmax + weighted sum; one row per pass.
    auto select_row = [&](int r, bool writeGap) {
        const float v = s_log[r * 65 + lane];
        const float g = s_exp[r * 65 + lane];
        unsigned long long act = ~0ull, sel = 0ull;
        float m0 = 0.f, v8 = 0.f;
#pragma unroll
        for (int tt = 0; tt < TOPK; tt++) {
            float c = ((act >> lane) & 1ull) ? v : -3.0e38f;
            c = wave_max(c);
            unsigned long long elig = __ballot(v == c) & act;   // lowest index wins ties
            int win = __builtin_ctzll(elig);
            sel |= 1ull << win;
            act &= ~(1ull << win);
            if (tt == 0) m0 = c;
            v8 = c;
        }
        float c9 = ((act >> lane) & 1ull) ? v : -3.0e38f;
        float v9 = wave_max(c9);
        float w = ((sel >> lane) & 1ull) ? __expf(v - m0) : 0.f;
        float Z = wave_sum(w);
        float O = wave_sum(w * g);
        if (lane == 0) {
            out[blockRow + r] = O / Z;
            if (writeGap) { s_gap[r] = v8 - v9; s_vb[r] = 0.5f * (v8 + v9); }
        }
    };

    for (int rr = 0; rr < 8; ++rr) select_row(wid * 8 + rr, true);
    __syncthreads();

    // fp64 fixup for near-tie rows, distributed: wave w handles rows r%4==w
    for (int r = wid; r < ROWS; r += 4) {
        if (!(s_gap[r] < TAUF)) continue;
        const float vbr = s_vb[r];
        const float ve = s_log[r * 65 + lane];
        unsigned long long cand = __ballot(fabsf(ve - vbr) <= TAUB);
        const f32x4* xq = (const f32x4*)(x + (size_t)(blockRow + r) * DDIM) + lane * 4;
        const f32x4 xv0 = xq[0], xv1 = xq[1], xv2 = xq[2], xv3 = xq[3];
        while (cand) {
            const int ce = __builtin_ctzll(cand);
            cand &= cand - 1;
            const f32x4* wq = (const f32x4*)(Wn + (size_t)ce * DDIM) + lane * 4;
            const f32x4 w0 = wq[0], w1 = wq[1], w2 = wq[2], w3 = wq[3];
            double s = 0.0;
#pragma unroll
            for (int i = 0; i < 4; i++) s = fma((double)xv0[i], (double)w0[i], s);
#pragma unroll
            for (int i = 0; i < 4; i++) s = fma((double)xv1[i], (double)w1[i], s);
#pragma unroll
            for (int i = 0; i < 4; i++) s = fma((double)xv2[i], (double)w2[i], s);
#pragma unroll
            for (int i = 0; i < 4; i++) s = fma((double)xv3[i], (double)w3[i], s);
#pragma unroll
            for (int off = 32; off > 0; off >>= 1) s += __shfl_xor(s, off);
            s += (double)bn[ce];
            if (lane == 0) s_log[r * 65 + ce] = (float)s;
        }
    }
    __syncthreads();

    // re-select flagged rows with corrected logits
    for (int rr = 0; rr < 8; ++rr) {
        const int r = wid * 8 + rr;
        if (s_gap[r] < TAUF) select_row(r, false);
    }
}

extern "C" void kernel_launch(void* const* d_in, const int* in_sizes, int n_in,
                              void* d_out, int out_size, void* d_ws, size_t ws_size,
                              hipStream_t stream)
{
    // setup_inputs order: x, Wg, bg, Wn, bn, We, noise  (Wg/bg/noise are dead code)
    const float* x  = (const float*)d_in[0];
    const float* Wn = (const float*)d_in[3];
    const float* bn = (const float*)d_in[4];
    const float* We = (const float*)d_in[5];
    float* out = (float*)d_out;

    const int B = in_sizes[0] / DDIM;           // 65536
    const int grid = B / ROWS;                  // 2048

    const size_t need = (size_t)NTILE * WTILE;  // 384 KiB permuted W
    if (d_ws != nullptr && ws_size >= need) {
        conv_w_kernel<<<(NEXP * DDIM / 8) / 256, 256, 0, stream>>>(Wn, We, (char*)d_ws);
        moe_kernel<1><<<grid, 256, 0, stream>>>(x, Wn, bn, We, (const char*)d_ws, out);
    } else {
        moe_kernel<0><<<grid, 256, 0, stream>>>(x, Wn, bn, We, nullptr, out);
    }
}